// Round 1
// baseline (964.785 us; speedup 1.0000x reference)
//
#include <hip/hip_runtime.h>

// MoE top-2, E=8, T=8192, H=1024, I=2816. bf16 MFMA grouped-GEMM pipeline.
// R1: correctness-first structure. 128x128x64 tiles, padded LDS (72), inline-asm MFMA.

#define T_TOK 8192
#define H_DIM 1024
#define I_DIM 2816
#define NEXP  8
#define CAP   8192

typedef short bf16x8 __attribute__((ext_vector_type(8)));
typedef float f32x4  __attribute__((ext_vector_type(4)));

static __device__ __forceinline__ unsigned short f2bf(float f) {
  unsigned u = __float_as_uint(f);
  u = u + 0x7fffu + ((u >> 16) & 1u);   // RNE
  return (unsigned short)(u >> 16);
}

// D = A(16x32) * B(32x16) + D, bf16 in, f32 out. A/B frag: k = 8*(lane>>4)+j; C/D: col=lane&15,row=4*(lane>>4)+q
#define MFMA16x16x32(acc, a, b) \
  asm("v_mfma_f32_16x16x32_bf16 %0, %1, %2, %0" : "+v"(acc) : "v"(a), "v"(b))

// ---------------- router: logits, top-2 softmax, expert lists, x->bf16 ----------------
__global__ __launch_bounds__(256) void router_kernel(
    const float* __restrict__ x, const float* __restrict__ wr,
    int* __restrict__ cnt, int* __restrict__ tokL, float* __restrict__ wgtL,
    unsigned short* __restrict__ xb) {
  __shared__ float rw[NEXP * H_DIM];    // 32 KB
  int tid = threadIdx.x;
#pragma unroll
  for (int it = 0; it < 8; ++it) {
    int i4 = it * 256 + tid;
    ((float4*)rw)[i4] = ((const float4*)wr)[i4];
  }
  __syncthreads();
  int wid = tid >> 6, lane = tid & 63;
  int t = blockIdx.x * 4 + wid;         // one wave per token
  float a[NEXP];
#pragma unroll
  for (int e = 0; e < NEXP; ++e) a[e] = 0.f;
#pragma unroll
  for (int hc = 0; hc < H_DIM / 64; ++hc) {
    int h = hc * 64 + lane;
    float xv = x[(size_t)t * H_DIM + h];
    xb[(size_t)t * H_DIM + h] = f2bf(xv);
#pragma unroll
    for (int e = 0; e < NEXP; ++e) a[e] += xv * rw[e * H_DIM + h];
  }
#pragma unroll
  for (int e = 0; e < NEXP; ++e) {
    float v = a[e];
    for (int off = 32; off > 0; off >>= 1) v += __shfl_xor(v, off, 64);
    a[e] = v;
  }
  if (lane == 0) {
    int e1 = 0; float l1 = a[0];
#pragma unroll
    for (int e = 1; e < NEXP; ++e) if (a[e] > l1) { l1 = a[e]; e1 = e; }
    int e2 = -1; float l2 = -3.4e38f;
#pragma unroll
    for (int e = 0; e < NEXP; ++e) if (e != e1 && a[e] > l2) { l2 = a[e]; e2 = e; }
    float q = expf(l2 - l1);
    float w1 = 1.f / (1.f + q);
    float w2 = q * w1;
    int p1 = atomicAdd(&cnt[e1], 1);
    tokL[e1 * CAP + p1] = t; wgtL[e1 * CAP + p1] = w1;
    int p2 = atomicAdd(&cnt[e2], 1);
    tokL[e2 * CAP + p2] = t; wgtL[e2 * CAP + p2] = w2;
  }
}

__global__ void scan_kernel(const int* __restrict__ cnt, int* __restrict__ offs) {
  if (threadIdx.x == 0) {
    int s = 0;
    for (int e = 0; e < NEXP; ++e) { offs[e] = s; s += cnt[e]; }
  }
}

// ---------------- transpose last-2-dims + f32->bf16: src [M][R][C] -> dst [M][C][R] ----------------
__global__ __launch_bounds__(256) void transpose_kernel(
    const float* __restrict__ src, unsigned short* __restrict__ dst, int R, int C) {
  __shared__ float tile[64][65];        // pad 65: conflict-free both phases
  int m = blockIdx.z;
  int r0 = blockIdx.y * 64, c0 = blockIdx.x * 64;
  const float* s = src + (size_t)m * R * C;
  unsigned short* d = dst + (size_t)m * R * C;
  int tid = threadIdx.x;
#pragma unroll
  for (int it = 0; it < 4; ++it) {
    int id4 = it * 256 + tid;
    int r = id4 >> 4, c4 = (id4 & 15) * 4;
    float4 v = *(const float4*)(s + (size_t)(r0 + r) * C + c0 + c4);
    tile[r][c4] = v.x; tile[r][c4 + 1] = v.y; tile[r][c4 + 2] = v.z; tile[r][c4 + 3] = v.w;
  }
  __syncthreads();
#pragma unroll
  for (int it = 0; it < 4; ++it) {
    int qd = it * 256 + tid;
    int c = qd >> 4, rq = (qd & 15) * 4;
    ushort4 o;
    o.x = f2bf(tile[rq][c]);     o.y = f2bf(tile[rq + 1][c]);
    o.z = f2bf(tile[rq + 2][c]); o.w = f2bf(tile[rq + 3][c]);
    *(ushort4*)(d + (size_t)(c0 + c) * R + r0 + rq) = o;
  }
}

// ---------------- gate+up fused grouped GEMM + silu*mul -> h (bf16) ----------------
__global__ __launch_bounds__(256) void gateup_kernel(
    const unsigned short* __restrict__ xb,
    const unsigned short* __restrict__ wgT,   // [E][I][H] bf16
    const unsigned short* __restrict__ wuT,   // [E][I][H] bf16
    const int* __restrict__ cnt, const int* __restrict__ offs,
    const int* __restrict__ tokL,
    unsigned short* __restrict__ hbuf) {      // [16384][I] bf16, rows compact per expert
  int e = blockIdx.z;
  int cnt_e = cnt[e];
  int m0 = blockIdx.y * 128;
  if (m0 >= cnt_e) return;
  int n0 = blockIdx.x * 128;
  int rcnt = cnt_e - m0; if (rcnt > 128) rcnt = 128;

  __shared__ unsigned short As[128][72], Gs[128][72], Us[128][72];  // pad 72: 144B row, 16B-aligned, 2-way-free
  __shared__ int trow[128];
  int tid = threadIdx.x;
  if (tid < 128) trow[tid] = (tid < rcnt) ? tokL[e * CAP + m0 + tid] : 0;
  __syncthreads();

  int lane = tid & 63, wid = tid >> 6;
  int wr = wid >> 1, wc = wid & 1;
  int fr = lane & 15, fg = lane >> 4;

  f32x4 accg[4][4], accu[4][4];
#pragma unroll
  for (int m = 0; m < 4; ++m)
#pragma unroll
    for (int n = 0; n < 4; ++n) { accg[m][n] = (f32x4)0.f; accu[m][n] = (f32x4)0.f; }

  for (int ks = 0; ks < H_DIM / 64; ++ks) {
    int k0 = ks * 64;
#pragma unroll
    for (int it = 0; it < 4; ++it) {
      int c = it * 256 + tid;
      int row = c >> 3, ch = c & 7;
      uint4 v = {0u, 0u, 0u, 0u};
      if (row < rcnt) v = *(const uint4*)(xb + (size_t)trow[row] * H_DIM + k0 + ch * 8);
      *(uint4*)(&As[row][ch * 8]) = v;
      uint4 g = *(const uint4*)(wgT + ((size_t)e * I_DIM + n0 + row) * H_DIM + k0 + ch * 8);
      *(uint4*)(&Gs[row][ch * 8]) = g;
      uint4 u = *(const uint4*)(wuT + ((size_t)e * I_DIM + n0 + row) * H_DIM + k0 + ch * 8);
      *(uint4*)(&Us[row][ch * 8]) = u;
    }
    __syncthreads();
#pragma unroll
    for (int kk = 0; kk < 2; ++kk) {
      bf16x8 am[4], bg[4], bu[4];
#pragma unroll
      for (int m = 0; m < 4; ++m)
        am[m] = *(const bf16x8*)(&As[wr * 64 + m * 16 + fr][kk * 32 + fg * 8]);
#pragma unroll
      for (int n = 0; n < 4; ++n) {
        bg[n] = *(const bf16x8*)(&Gs[wc * 64 + n * 16 + fr][kk * 32 + fg * 8]);
        bu[n] = *(const bf16x8*)(&Us[wc * 64 + n * 16 + fr][kk * 32 + fg * 8]);
      }
#pragma unroll
      for (int m = 0; m < 4; ++m)
#pragma unroll
        for (int n = 0; n < 4; ++n) {
          MFMA16x16x32(accg[m][n], am[m], bg[n]);
          MFMA16x16x32(accu[m][n], am[m], bu[n]);
        }
    }
    __syncthreads();
  }
  int hb = offs[e];
#pragma unroll
  for (int m = 0; m < 4; ++m)
#pragma unroll
    for (int q = 0; q < 4; ++q) {
      int row = wr * 64 + m * 16 + fg * 4 + q;
      if (row < rcnt) {
        size_t rbase = (size_t)(hb + m0 + row) * I_DIM + n0 + wc * 64;
#pragma unroll
        for (int n = 0; n < 4; ++n) {
          float g = accg[m][n][q], u = accu[m][n][q];
          float hv = g / (1.f + expf(-g)) * u;    // silu(g)*u
          hbuf[rbase + n * 16 + fr] = f2bf(hv);
        }
      }
    }
}

// ---------------- down grouped GEMM + weighted scatter-add ----------------
__global__ __launch_bounds__(256) void down_kernel(
    const unsigned short* __restrict__ hbuf,
    const unsigned short* __restrict__ wdT,   // [E][H][I] bf16
    const int* __restrict__ cnt, const int* __restrict__ offs,
    const int* __restrict__ tokL, const float* __restrict__ wgtL,
    float* __restrict__ out) {
  int e = blockIdx.z;
  int cnt_e = cnt[e];
  int m0 = blockIdx.y * 128;
  if (m0 >= cnt_e) return;
  int n0 = blockIdx.x * 128;
  int rcnt = cnt_e - m0; if (rcnt > 128) rcnt = 128;
  int hb = offs[e];

  __shared__ unsigned short As[128][72], Bs[128][72];
  int tid = threadIdx.x, lane = tid & 63, wid = tid >> 6;
  int wr = wid >> 1, wc = wid & 1, fr = lane & 15, fg = lane >> 4;

  f32x4 acc[4][4];
#pragma unroll
  for (int m = 0; m < 4; ++m)
#pragma unroll
    for (int n = 0; n < 4; ++n) acc[m][n] = (f32x4)0.f;

  for (int ks = 0; ks < I_DIM / 64; ++ks) {   // 44 steps
    int k0 = ks * 64;
#pragma unroll
    for (int it = 0; it < 4; ++it) {
      int c = it * 256 + tid;
      int row = c >> 3, ch = c & 7;
      uint4 v = {0u, 0u, 0u, 0u};
      if (row < rcnt) v = *(const uint4*)(hbuf + (size_t)(hb + m0 + row) * I_DIM + k0 + ch * 8);
      *(uint4*)(&As[row][ch * 8]) = v;
      uint4 b = *(const uint4*)(wdT + ((size_t)e * H_DIM + n0 + row) * I_DIM + k0 + ch * 8);
      *(uint4*)(&Bs[row][ch * 8]) = b;
    }
    __syncthreads();
#pragma unroll
    for (int kk = 0; kk < 2; ++kk) {
      bf16x8 am[4], bn[4];
#pragma unroll
      for (int m = 0; m < 4; ++m)
        am[m] = *(const bf16x8*)(&As[wr * 64 + m * 16 + fr][kk * 32 + fg * 8]);
#pragma unroll
      for (int n = 0; n < 4; ++n)
        bn[n] = *(const bf16x8*)(&Bs[wc * 64 + n * 16 + fr][kk * 32 + fg * 8]);
#pragma unroll
      for (int m = 0; m < 4; ++m)
#pragma unroll
        for (int n = 0; n < 4; ++n)
          MFMA16x16x32(acc[m][n], am[m], bn[n]);
    }
    __syncthreads();
  }
#pragma unroll
  for (int m = 0; m < 4; ++m)
#pragma unroll
    for (int q = 0; q < 4; ++q) {
      int row = wr * 64 + m * 16 + fg * 4 + q;
      if (row < rcnt) {
        float w = wgtL[e * CAP + m0 + row];
        int t = tokL[e * CAP + m0 + row];
        float* obase = out + (size_t)t * H_DIM + n0 + wc * 64;
#pragma unroll
        for (int n = 0; n < 4; ++n)
          atomicAdd(obase + n * 16 + fr, w * acc[m][n][q]);
      }
    }
}

extern "C" void kernel_launch(void* const* d_in, const int* in_sizes, int n_in,
                              void* d_out, int out_size, void* d_ws, size_t ws_size,
                              hipStream_t stream) {
  const float* x   = (const float*)d_in[0];
  const float* wr  = (const float*)d_in[1];
  const float* wg  = (const float*)d_in[2];
  const float* wu  = (const float*)d_in[3];
  const float* wd  = (const float*)d_in[4];
  float* out = (float*)d_out;

  // ws layout (~249 MB total)
  char* ws = (char*)d_ws;
  int*   cnt  = (int*)ws;                                   // @0, 32 B
  int*   offs = (int*)(ws + 64);                            // @64
  int*   tokL = (int*)(ws + 1024);                          // 256 KB
  float* wgtL = (float*)(ws + 1024 + (size_t)NEXP * CAP * 4);
  unsigned short* xb  = (unsigned short*)(ws + (1u << 20));
  unsigned short* wgT = (unsigned short*)(ws + (1u << 20) + (size_t)T_TOK * H_DIM * 2);
  unsigned short* wuT = wgT + (size_t)NEXP * I_DIM * H_DIM;
  unsigned short* wdT = wuT + (size_t)NEXP * I_DIM * H_DIM;
  unsigned short* hbuf = wdT + (size_t)NEXP * H_DIM * I_DIM;

  hipMemsetAsync(ws, 0, 64, stream);                              // counts
  hipMemsetAsync(d_out, 0, (size_t)out_size * 4, stream);         // atomics accumulate

  router_kernel<<<T_TOK / 4, 256, 0, stream>>>(x, wr, cnt, tokL, wgtL, xb);
  scan_kernel<<<1, 64, 0, stream>>>(cnt, offs);

  transpose_kernel<<<dim3(I_DIM / 64, H_DIM / 64, NEXP), 256, 0, stream>>>(wg, wgT, H_DIM, I_DIM);
  transpose_kernel<<<dim3(I_DIM / 64, H_DIM / 64, NEXP), 256, 0, stream>>>(wu, wuT, H_DIM, I_DIM);
  transpose_kernel<<<dim3(H_DIM / 64, I_DIM / 64, NEXP), 256, 0, stream>>>(wd, wdT, I_DIM, H_DIM);

  gateup_kernel<<<dim3(I_DIM / 128, CAP / 128, NEXP), 256, 0, stream>>>(
      xb, wgT, wuT, cnt, offs, tokL, hbuf);
  down_kernel<<<dim3(H_DIM / 128, CAP / 128, NEXP), 256, 0, stream>>>(
      hbuf, wdT, cnt, offs, tokL, wgtL, out);
}

// Round 2
// 687.134 us; speedup vs baseline: 1.4041x; 1.4041x over previous
//
#include <hip/hip_runtime.h>

// MoE top-2, E=8, T=8192, H=1024, I=2816. bf16 MFMA grouped-GEMM pipeline.
// R2: global_load_lds width=16 staging, linear LDS tiles + XOR swizzle
//     (pre-swizzled global source, swizzled ds_read), higher occupancy.

#define T_TOK 8192
#define H_DIM 1024
#define I_DIM 2816
#define NEXP  8
#define CAP   8192

typedef short bf16x8 __attribute__((ext_vector_type(8)));
typedef float f32x4  __attribute__((ext_vector_type(4)));

static __device__ __forceinline__ unsigned short f2bf(float f) {
  unsigned u = __float_as_uint(f);
  u = u + 0x7fffu + ((u >> 16) & 1u);   // RNE
  return (unsigned short)(u >> 16);
}

// D = A(16x32)*B(32x16)+D. A/B frag: k = 8*(lane>>4)+j; C/D: col=lane&15, row=4*(lane>>4)+q
#define MFMA16x16x32(acc, a, b) \
  asm("v_mfma_f32_16x16x32_bf16 %0, %1, %2, %0" : "+v"(acc) : "v"(a), "v"(b))

// async global->LDS, 16B/lane, 64 lanes = 1KB contiguous from uniform base
#define GLD16(g, l) \
  __builtin_amdgcn_global_load_lds((const __attribute__((address_space(1))) void*)(g), \
                                   (__attribute__((address_space(3))) void*)(l), 16, 0, 0)

// ---------------- router: logits, top-2 softmax, expert lists, x->bf16 ----------------
__global__ __launch_bounds__(256) void router_kernel(
    const float* __restrict__ x, const float* __restrict__ wr,
    int* __restrict__ cnt, int* __restrict__ tokL, float* __restrict__ wgtL,
    unsigned short* __restrict__ xb) {
  __shared__ float rw[NEXP * H_DIM];    // 32 KB
  int tid = threadIdx.x;
#pragma unroll
  for (int it = 0; it < 8; ++it) {
    int i4 = it * 256 + tid;
    ((float4*)rw)[i4] = ((const float4*)wr)[i4];
  }
  __syncthreads();
  int wid = tid >> 6, lane = tid & 63;
  int t = blockIdx.x * 4 + wid;         // one wave per token
  float a[NEXP];
#pragma unroll
  for (int e = 0; e < NEXP; ++e) a[e] = 0.f;
#pragma unroll
  for (int hc = 0; hc < H_DIM / 64; ++hc) {
    int h = hc * 64 + lane;
    float xv = x[(size_t)t * H_DIM + h];
    xb[(size_t)t * H_DIM + h] = f2bf(xv);
#pragma unroll
    for (int e = 0; e < NEXP; ++e) a[e] += xv * rw[e * H_DIM + h];
  }
#pragma unroll
  for (int e = 0; e < NEXP; ++e) {
    float v = a[e];
    for (int off = 32; off > 0; off >>= 1) v += __shfl_xor(v, off, 64);
    a[e] = v;
  }
  if (lane == 0) {
    int e1 = 0; float l1 = a[0];
#pragma unroll
    for (int e = 1; e < NEXP; ++e) if (a[e] > l1) { l1 = a[e]; e1 = e; }
    int e2 = -1; float l2 = -3.4e38f;
#pragma unroll
    for (int e = 0; e < NEXP; ++e) if (e != e1 && a[e] > l2) { l2 = a[e]; e2 = e; }
    float q = expf(l2 - l1);
    float w1 = 1.f / (1.f + q);
    float w2 = q * w1;
    int p1 = atomicAdd(&cnt[e1], 1);
    tokL[e1 * CAP + p1] = t; wgtL[e1 * CAP + p1] = w1;
    int p2 = atomicAdd(&cnt[e2], 1);
    tokL[e2 * CAP + p2] = t; wgtL[e2 * CAP + p2] = w2;
  }
}

__global__ void scan_kernel(const int* __restrict__ cnt, int* __restrict__ offs) {
  if (threadIdx.x == 0) {
    int s = 0;
    for (int e = 0; e < NEXP; ++e) { offs[e] = s; s += cnt[e]; }
  }
}

// ---------------- transpose last-2-dims + f32->bf16: src [M][R][C] -> dst [M][C][R] ----------------
__global__ __launch_bounds__(256) void transpose_kernel(
    const float* __restrict__ src, unsigned short* __restrict__ dst, int R, int C) {
  __shared__ float tile[64][65];
  int m = blockIdx.z;
  int r0 = blockIdx.y * 64, c0 = blockIdx.x * 64;
  const float* s = src + (size_t)m * R * C;
  unsigned short* d = dst + (size_t)m * R * C;
  int tid = threadIdx.x;
#pragma unroll
  for (int it = 0; it < 4; ++it) {
    int id4 = it * 256 + tid;
    int r = id4 >> 4, c4 = (id4 & 15) * 4;
    float4 v = *(const float4*)(s + (size_t)(r0 + r) * C + c0 + c4);
    tile[r][c4] = v.x; tile[r][c4 + 1] = v.y; tile[r][c4 + 2] = v.z; tile[r][c4 + 3] = v.w;
  }
  __syncthreads();
#pragma unroll
  for (int it = 0; it < 4; ++it) {
    int qd = it * 256 + tid;
    int c = qd >> 4, rq = (qd & 15) * 4;
    ushort4 o;
    o.x = f2bf(tile[rq][c]);     o.y = f2bf(tile[rq + 1][c]);
    o.z = f2bf(tile[rq + 2][c]); o.w = f2bf(tile[rq + 3][c]);
    *(ushort4*)(d + (size_t)(c0 + c) * R + r0 + rq) = o;
  }
}

// ---------------- gate+up fused grouped GEMM + silu*mul -> h (bf16) ----------------
// LDS tiles linear [128][64] bf16. Physical (row,c16) holds logical (row, c16^(row&7)).
// Staged via GLD16: chunk ch covers rows ch*8..ch*8+7; lane l -> (row=ch*8+(l>>3), c16=l&7),
// so lane source col16 = (l&7)^(l>>3). Reads XOR c16 with (row&7).
__global__ __launch_bounds__(256) void gateup_kernel(
    const unsigned short* __restrict__ xb,
    const unsigned short* __restrict__ wgT,   // [E][I][H] bf16
    const unsigned short* __restrict__ wuT,   // [E][I][H] bf16
    const int* __restrict__ cnt, const int* __restrict__ offs,
    const int* __restrict__ tokL,
    unsigned short* __restrict__ hbuf) {      // [16384][I] bf16, rows compact per expert
  int e = blockIdx.z;
  int cnt_e = cnt[e];
  int m0 = blockIdx.y * 128;
  if (m0 >= cnt_e) return;
  int n0 = blockIdx.x * 128;
  int rcnt = cnt_e - m0; if (rcnt > 128) rcnt = 128;

  __shared__ unsigned short As[128 * 64], Gs[128 * 64], Us[128 * 64];  // 48 KB
  __shared__ int trow[128];
  int tid = threadIdx.x;
  if (tid < 128) trow[tid] = tokL[e * CAP + m0 + ((tid < rcnt) ? tid : 0)];
  __syncthreads();

  int lane = tid & 63, wid = tid >> 6;
  int lr = lane >> 3;                        // 0..7 = row within chunk
  int csrc = ((lane & 7) ^ lr) * 8;          // pre-swizzled source col (shorts)

  const unsigned short* baseA[4];
  const unsigned short* baseG[4];
  const unsigned short* baseU[4];
  int ldso[4];
#pragma unroll
  for (int i = 0; i < 4; ++i) {
    int chunk = wid * 4 + i;
    int row = chunk * 8 + lr;
    baseA[i] = xb + (size_t)trow[row] * H_DIM + csrc;
    size_t wrow = ((size_t)e * I_DIM + n0 + row) * H_DIM + csrc;
    baseG[i] = wgT + wrow;
    baseU[i] = wuT + wrow;
    ldso[i] = chunk * 512;                   // shorts (1KB per chunk)
  }

  int wr = wid >> 1, wc = wid & 1;
  int fr = lane & 15, fg = lane >> 4;
  int fsw = (fr & 7);                        // row&7 for all frag rows

  f32x4 accg[4][4], accu[4][4];
#pragma unroll
  for (int m = 0; m < 4; ++m)
#pragma unroll
    for (int n = 0; n < 4; ++n) { accg[m][n] = (f32x4)0.f; accu[m][n] = (f32x4)0.f; }

  for (int ks = 0; ks < H_DIM / 64; ++ks) {
    int k0 = ks * 64;
#pragma unroll
    for (int i = 0; i < 4; ++i) {
      GLD16(baseA[i] + k0, As + ldso[i]);
      GLD16(baseG[i] + k0, Gs + ldso[i]);
      GLD16(baseU[i] + k0, Us + ldso[i]);
    }
    __syncthreads();
#pragma unroll
    for (int kk = 0; kk < 2; ++kk) {
      int cb = ((kk * 4 + fg) ^ fsw) * 8;    // swizzled col offset (shorts)
      bf16x8 am[4], bg[4], bu[4];
#pragma unroll
      for (int m = 0; m < 4; ++m)
        am[m] = *(const bf16x8*)(As + (wr * 64 + m * 16 + fr) * 64 + cb);
#pragma unroll
      for (int n = 0; n < 4; ++n) {
        bg[n] = *(const bf16x8*)(Gs + (wc * 64 + n * 16 + fr) * 64 + cb);
        bu[n] = *(const bf16x8*)(Us + (wc * 64 + n * 16 + fr) * 64 + cb);
      }
#pragma unroll
      for (int m = 0; m < 4; ++m)
#pragma unroll
        for (int n = 0; n < 4; ++n) {
          MFMA16x16x32(accg[m][n], am[m], bg[n]);
          MFMA16x16x32(accu[m][n], am[m], bu[n]);
        }
    }
    __syncthreads();
  }
  int hb = offs[e];
#pragma unroll
  for (int m = 0; m < 4; ++m)
#pragma unroll
    for (int q = 0; q < 4; ++q) {
      int row = wr * 64 + m * 16 + fg * 4 + q;
      if (row < rcnt) {
        size_t rbase = (size_t)(hb + m0 + row) * I_DIM + n0 + wc * 64;
#pragma unroll
        for (int n = 0; n < 4; ++n) {
          float g = accg[m][n][q], u = accu[m][n][q];
          float hv = g / (1.f + expf(-g)) * u;    // silu(g)*u
          hbuf[rbase + n * 16 + fr] = f2bf(hv);
        }
      }
    }
}

// ---------------- down grouped GEMM + weighted scatter-add ----------------
__global__ __launch_bounds__(256) void down_kernel(
    const unsigned short* __restrict__ hbuf,
    const unsigned short* __restrict__ wdT,   // [E][H][I] bf16
    const int* __restrict__ cnt, const int* __restrict__ offs,
    const int* __restrict__ tokL, const float* __restrict__ wgtL,
    float* __restrict__ out) {
  int e = blockIdx.z;
  int cnt_e = cnt[e];
  int m0 = blockIdx.y * 128;
  if (m0 >= cnt_e) return;
  int n0 = blockIdx.x * 128;
  int rcnt = cnt_e - m0; if (rcnt > 128) rcnt = 128;
  int hb = offs[e];

  __shared__ unsigned short As[128 * 64], Bs[128 * 64];   // 32 KB
  int tid = threadIdx.x, lane = tid & 63, wid = tid >> 6;
  int lr = lane >> 3;
  int csrc = ((lane & 7) ^ lr) * 8;

  const unsigned short* baseA[4];
  const unsigned short* baseB[4];
  int ldso[4];
#pragma unroll
  for (int i = 0; i < 4; ++i) {
    int chunk = wid * 4 + i;
    int row = chunk * 8 + lr;
    int rowc = (row < rcnt) ? row : (rcnt - 1);           // clamp: stay in-expert
    baseA[i] = hbuf + (size_t)(hb + m0 + rowc) * I_DIM + csrc;
    baseB[i] = wdT + ((size_t)e * H_DIM + n0 + row) * I_DIM + csrc;
    ldso[i] = chunk * 512;
  }

  int wr = wid >> 1, wc = wid & 1, fr = lane & 15, fg = lane >> 4;
  int fsw = (fr & 7);

  f32x4 acc[4][4];
#pragma unroll
  for (int m = 0; m < 4; ++m)
#pragma unroll
    for (int n = 0; n < 4; ++n) acc[m][n] = (f32x4)0.f;

  for (int ks = 0; ks < I_DIM / 64; ++ks) {   // 44 steps
    int k0 = ks * 64;
#pragma unroll
    for (int i = 0; i < 4; ++i) {
      GLD16(baseA[i] + k0, As + ldso[i]);
      GLD16(baseB[i] + k0, Bs + ldso[i]);
    }
    __syncthreads();
#pragma unroll
    for (int kk = 0; kk < 2; ++kk) {
      int cb = ((kk * 4 + fg) ^ fsw) * 8;
      bf16x8 am[4], bn[4];
#pragma unroll
      for (int m = 0; m < 4; ++m)
        am[m] = *(const bf16x8*)(As + (wr * 64 + m * 16 + fr) * 64 + cb);
#pragma unroll
      for (int n = 0; n < 4; ++n)
        bn[n] = *(const bf16x8*)(Bs + (wc * 64 + n * 16 + fr) * 64 + cb);
#pragma unroll
      for (int m = 0; m < 4; ++m)
#pragma unroll
        for (int n = 0; n < 4; ++n)
          MFMA16x16x32(acc[m][n], am[m], bn[n]);
    }
    __syncthreads();
  }
#pragma unroll
  for (int m = 0; m < 4; ++m)
#pragma unroll
    for (int q = 0; q < 4; ++q) {
      int row = wr * 64 + m * 16 + fg * 4 + q;
      if (row < rcnt) {
        float w = wgtL[e * CAP + m0 + row];
        int t = tokL[e * CAP + m0 + row];
        float* obase = out + (size_t)t * H_DIM + n0 + wc * 64;
#pragma unroll
        for (int n = 0; n < 4; ++n)
          atomicAdd(obase + n * 16 + fr, w * acc[m][n][q]);
      }
    }
}

extern "C" void kernel_launch(void* const* d_in, const int* in_sizes, int n_in,
                              void* d_out, int out_size, void* d_ws, size_t ws_size,
                              hipStream_t stream) {
  const float* x   = (const float*)d_in[0];
  const float* wr  = (const float*)d_in[1];
  const float* wg  = (const float*)d_in[2];
  const float* wu  = (const float*)d_in[3];
  const float* wd  = (const float*)d_in[4];
  float* out = (float*)d_out;

  char* ws = (char*)d_ws;
  int*   cnt  = (int*)ws;
  int*   offs = (int*)(ws + 64);
  int*   tokL = (int*)(ws + 1024);
  float* wgtL = (float*)(ws + 1024 + (size_t)NEXP * CAP * 4);
  unsigned short* xb  = (unsigned short*)(ws + (1u << 20));
  unsigned short* wgT = (unsigned short*)(ws + (1u << 20) + (size_t)T_TOK * H_DIM * 2);
  unsigned short* wuT = wgT + (size_t)NEXP * I_DIM * H_DIM;
  unsigned short* wdT = wuT + (size_t)NEXP * I_DIM * H_DIM;
  unsigned short* hbuf = wdT + (size_t)NEXP * H_DIM * I_DIM;

  hipMemsetAsync(ws, 0, 64, stream);
  hipMemsetAsync(d_out, 0, (size_t)out_size * 4, stream);

  router_kernel<<<T_TOK / 4, 256, 0, stream>>>(x, wr, cnt, tokL, wgtL, xb);
  scan_kernel<<<1, 64, 0, stream>>>(cnt, offs);

  transpose_kernel<<<dim3(I_DIM / 64, H_DIM / 64, NEXP), 256, 0, stream>>>(wg, wgT, H_DIM, I_DIM);
  transpose_kernel<<<dim3(I_DIM / 64, H_DIM / 64, NEXP), 256, 0, stream>>>(wu, wuT, H_DIM, I_DIM);
  transpose_kernel<<<dim3(H_DIM / 64, I_DIM / 64, NEXP), 256, 0, stream>>>(wd, wdT, I_DIM, H_DIM);

  gateup_kernel<<<dim3(I_DIM / 128, CAP / 128, NEXP), 256, 0, stream>>>(
      xb, wgT, wuT, cnt, offs, tokL, hbuf);
  down_kernel<<<dim3(H_DIM / 128, CAP / 128, NEXP), 256, 0, stream>>>(
      hbuf, wdT, cnt, offs, tokL, wgtL, out);
}